// Round 2
// baseline (1922.029 us; speedup 1.0000x reference)
//
#include <hip/hip_runtime.h>

typedef unsigned int u32;
typedef unsigned short u16;

#define NEG 0.01f
#define BN_EPS 1e-5f

__device__ __forceinline__ float bl(u32 u){ union { u32 i; float f; } c; c.i = u << 16; return c.f; }
__device__ __forceinline__ float bh(u32 u){ union { u32 i; float f; } c; c.i = u & 0xFFFF0000u; return c.f; }
__device__ __forceinline__ float b2f(u16 u){ union { u32 i; float f; } c; c.i = ((u32)u) << 16; return c.f; }
__device__ __forceinline__ u16 r2b(u32 fb){ u32 t = fb + 0x7FFFu + ((fb >> 16) & 1u); return (u16)(t >> 16); }
__device__ __forceinline__ u16 f2b(float f){ union { float f; u32 i; } c; c.f = f; return r2b(c.i); }
__device__ __forceinline__ float leaky(float v){ return v > 0.f ? v : NEG * v; }

// scalar load from tensor that is either bf16 (u16) or fp32, per runtime flag
__device__ __forceinline__ float ldf(const void* p, int i, int isf32){
  return isf32 ? ((const float*)p)[i] : b2f(((const u16*)p)[i]);
}
__device__ __forceinline__ u16 ld16(const void* p, int i, int isf32){
  return isf32 ? r2b(((const u32*)p)[i]) : ((const u16*)p)[i];
}

// ---------------------------------------------------------------------------
// Kernel 0: dtype detection. bf16 data: both u16 halves of each word decode to
// plausible |x| in [2^-30, 2^8] (~100%). fp32 data: low half is random
// mantissa bits (~15% pass). flag=1 -> fp32.
// ---------------------------------------------------------------------------
__global__ void k_detect(const u32* __restrict__ des, int* __restrict__ flag)
{
  int lane = threadIdx.x & 63;
  int cnt = 0;
  for (int j = 0; j < 4; ++j) {
    u32 w = des[lane * 4 + j];
    u32 lo = w & 0xFFFFu, hi = w >> 16;
    int el = (lo >> 7) & 0xFF, eh = (hi >> 7) & 0xFF;
    int pl = (lo == 0u) || (el >= 97 && el <= 135);
    int ph = (hi == 0u) || (eh >= 97 && eh <= 135);
    cnt += (pl && ph) ? 1 : 0;
  }
  #pragma unroll
  for (int o = 32; o > 0; o >>= 1) cnt += __shfl_down(cnt, o);
  if (lane == 0) flag[0] = (cnt < 128) ? 1 : 0;
}

// ---------------------------------------------------------------------------
// Kernel 1: feature fusion. x[n][64] = sum of 3 leaky(bn(linear)) branches.
// Persistent blocks (1/CU, ~112KB LDS). Wave-per-node, lane = out channel h.
// fp32 inputs are rounded to bf16 during staging (threshold is 2% of max).
// ---------------------------------------------------------------------------
#define FUSE_GROUP 8

__global__ __launch_bounds__(256) void k_fuse(
    const void* __restrict__ des, const void* __restrict__ nump, const void* __restrict__ catp,
    const void* __restrict__ desW, const void* __restrict__ desB,
    const void* __restrict__ numW, const void* __restrict__ numB,
    const void* __restrict__ catW, const void* __restrict__ catB,
    const void* __restrict__ dg, const void* __restrict__ dbe, const void* __restrict__ dm, const void* __restrict__ dv,
    const void* __restrict__ ng, const void* __restrict__ nbe, const void* __restrict__ nm, const void* __restrict__ nv,
    const void* __restrict__ cg, const void* __restrict__ cbe, const void* __restrict__ cm, const void* __restrict__ cv,
    const int* __restrict__ flagp, float* __restrict__ x, int n)
{
  __shared__ __align__(16) u16 sW[64 * 776];
  __shared__ __align__(16) u16 sRow[FUSE_GROUP * 768];
  __shared__ u16 sNum[FUSE_GROUP * 8];
  __shared__ u16 sCat[FUSE_GROUP * 8];

  const int tid = threadIdx.x;
  const int lane = tid & 63;
  const int w = tid >> 6;
  const int h = lane;
  const int isf32 = flagp[0];

  // stage des_W (64x768) into LDS, padded rows (bf16 either way)
  if (!isf32) {
    const u16* wp16 = (const u16*)desW;
    for (int i = tid * 8; i < 64 * 768; i += 256 * 8) {
      int r = i / 768, c = i % 768;
      uint4 q = *(const uint4*)(wp16 + i);
      *(uint4*)(&sW[r * 776 + c]) = q;
    }
  } else {
    const float* wf = (const float*)desW;
    for (int i = tid * 8; i < 64 * 768; i += 256 * 8) {
      uint4 a = *(const uint4*)(wf + i);
      uint4 b = *(const uint4*)(wf + i + 4);
      uint4 q;
      q.x = (u32)r2b(a.x) | ((u32)r2b(a.y) << 16);
      q.y = (u32)r2b(a.z) | ((u32)r2b(a.w) << 16);
      q.z = (u32)r2b(b.x) | ((u32)r2b(b.y) << 16);
      q.w = (u32)r2b(b.z) | ((u32)r2b(b.w) << 16);
      int r = i / 768, c = i % 768;
      *(uint4*)(&sW[r * 776 + c]) = q;
    }
  }

  // per-lane (per output channel) constants: small weights + folded BN affine
  float nw[5], cw[6];
  for (int j = 0; j < 5; ++j) nw[j] = ldf(numW, h * 5 + j, isf32);
  for (int j = 0; j < 6; ++j) cw[j] = ldf(catW, h * 6 + j, isf32);
  float Ad = ldf(dg, h, isf32) * rsqrtf(ldf(dv, h, isf32) + BN_EPS);
  float Bd = (ldf(desB, h, isf32) - ldf(dm, h, isf32)) * Ad + ldf(dbe, h, isf32);
  float An = ldf(ng, h, isf32) * rsqrtf(ldf(nv, h, isf32) + BN_EPS);
  float Bn = (ldf(numB, h, isf32) - ldf(nm, h, isf32)) * An + ldf(nbe, h, isf32);
  float Ac = ldf(cg, h, isf32) * rsqrtf(ldf(cv, h, isf32) + BN_EPS);
  float Bc = (ldf(catB, h, isf32) - ldf(cm, h, isf32)) * Ac + ldf(cbe, h, isf32);
  __syncthreads();

  for (int base = blockIdx.x * FUSE_GROUP; base < n; base += gridDim.x * FUSE_GROUP) {
    // stage FUSE_GROUP des rows
    if (!isf32) {
      const u16* df = (const u16*)des;
      for (int idx = tid; idx < FUSE_GROUP * 96; idx += 256) {
        int r = idx / 96, c = (idx % 96) * 8;
        if (base + r < n)
          *(uint4*)(&sRow[r * 768 + c]) = *(const uint4*)(df + (size_t)(base + r) * 768 + c);
      }
    } else {
      const float* df = (const float*)des;
      for (int idx = tid; idx < FUSE_GROUP * 96; idx += 256) {
        int r = idx / 96, c = (idx % 96) * 8;
        if (base + r < n) {
          const float* rp = df + (size_t)(base + r) * 768 + c;
          uint4 a = *(const uint4*)rp;
          uint4 b = *(const uint4*)(rp + 4);
          uint4 q;
          q.x = (u32)r2b(a.x) | ((u32)r2b(a.y) << 16);
          q.y = (u32)r2b(a.z) | ((u32)r2b(a.w) << 16);
          q.z = (u32)r2b(b.x) | ((u32)r2b(b.y) << 16);
          q.w = (u32)r2b(b.z) | ((u32)r2b(b.w) << 16);
          *(uint4*)(&sRow[r * 768 + c]) = q;
        }
      }
    }
    if (tid < FUSE_GROUP * 5) {
      int r = tid / 5, j = tid % 5;
      if (base + r < n) sNum[r * 8 + j] = ld16(nump, (base + r) * 5 + j, isf32);
    }
    if (tid >= 64 && tid < 64 + FUSE_GROUP * 6) {
      int t2 = tid - 64; int r = t2 / 6, j = t2 % 6;
      if (base + r < n) sCat[r * 8 + j] = ld16(catp, (base + r) * 6 + j, isf32);
    }
    __syncthreads();

    for (int sub = 0; sub < 2; ++sub) {
      int row = 2 * w + sub;
      int node = base + row;
      if (node < n) {
        const u16* rp = &sRow[row * 768];
        const u16* wp = &sW[h * 776];
        float a0 = 0.f, a1 = 0.f;
        #pragma unroll 4
        for (int kk = 0; kk < 768; kk += 8) {
          uint4 ua = *(const uint4*)(rp + kk);
          uint4 uw = *(const uint4*)(wp + kk);
          a0 = fmaf(bl(ua.x), bl(uw.x), a0); a1 = fmaf(bh(ua.x), bh(uw.x), a1);
          a0 = fmaf(bl(ua.y), bl(uw.y), a0); a1 = fmaf(bh(ua.y), bh(uw.y), a1);
          a0 = fmaf(bl(ua.z), bl(uw.z), a0); a1 = fmaf(bh(ua.z), bh(uw.z), a1);
          a0 = fmaf(bl(ua.w), bl(uw.w), a0); a1 = fmaf(bh(ua.w), bh(uw.w), a1);
        }
        float yd = leaky((a0 + a1) * Ad + Bd);
        float an = 0.f;
        for (int j = 0; j < 5; ++j) an = fmaf(b2f(sNum[row * 8 + j]), nw[j], an);
        float yn = leaky(an * An + Bn);
        float ac = 0.f;
        for (int j = 0; j < 6; ++j) ac = fmaf(b2f(sCat[row * 8 + j]), cw[j], ac);
        float yc = leaky(ac * Ac + Bc);
        x[(size_t)node * 64 + h] = yd + yn + yc;
      }
    }
    __syncthreads();
  }
}

// ---------------------------------------------------------------------------
// Kernel 2: in-degree histogram over dst
// ---------------------------------------------------------------------------
__global__ void k_hist(const int* __restrict__ ei, int E, int* __restrict__ deg)
{
  int e = blockIdx.x * 256 + threadIdx.x;
  if (e < E) atomicAdd(&deg[ei[E + e]], 1);
}

// ---------------------------------------------------------------------------
// Kernel 3: exclusive prefix sum (single block, 1024 threads, serial tiles)
// ---------------------------------------------------------------------------
__global__ __launch_bounds__(1024) void k_scan(const int* __restrict__ deg, int* __restrict__ offs, int n)
{
  __shared__ int wsum[16];
  __shared__ int carry;
  const int tid = threadIdx.x, lane = tid & 63, w = tid >> 6;
  if (tid == 0) carry = 0;
  __syncthreads();
  for (int base = 0; base < n; base += 1024) {
    int i = base + tid;
    int v = (i < n) ? deg[i] : 0;
    int s = v;
    #pragma unroll
    for (int o = 1; o < 64; o <<= 1) { int t = __shfl_up(s, o); if (lane >= o) s += t; }
    if (lane == 63) wsum[w] = s;
    __syncthreads();
    if (w == 0 && lane < 16) {
      int t = wsum[lane];
      #pragma unroll
      for (int o = 1; o < 16; o <<= 1) { int u = __shfl_up(t, o); if (lane >= o) t += u; }
      wsum[lane] = t;
    }
    __syncthreads();
    int wbase = (w == 0) ? 0 : wsum[w - 1];
    if (i < n) offs[i] = carry + wbase + (s - v);
    __syncthreads();
    if (tid == 0) carry += wsum[15];
    __syncthreads();
  }
  if (tid == 0) offs[n] = carry;
}

// ---------------------------------------------------------------------------
// Kernel 4: CSR placement. packed = src | (rel << 17)   (N=1e5 < 2^17)
// ---------------------------------------------------------------------------
__global__ void k_place(const int* __restrict__ ei, const int* __restrict__ et, int E,
                        const int* __restrict__ offs, int* __restrict__ cur, int* __restrict__ packed)
{
  int e = blockIdx.x * 256 + threadIdx.x;
  if (e < E) {
    int d = ei[E + e];
    int pos = offs[d] + atomicAdd(&cur[d], 1);
    packed[pos] = ei[e] | (et[e] << 17);
  }
}

// ---------------------------------------------------------------------------
// Kernel 5: per-node aggregation (wave-per-node, lane = channel) +
// relation transform + mean + classifier, all fused.
// ---------------------------------------------------------------------------
__global__ __launch_bounds__(256) void k_agg(
    const float* __restrict__ x, const int* __restrict__ offs, const int* __restrict__ packed,
    const void* __restrict__ rgcnW, const void* __restrict__ W1, const void* __restrict__ b1,
    const void* __restrict__ W2, const void* __restrict__ b2,
    const int* __restrict__ flagp, void* __restrict__ outp, int n)
{
  __shared__ u32 sWT[64 * 64];   // [k][h] : low16 = W0[h][k], high16 = W1[h][k]
  __shared__ u16 sW1T[64 * 32];  // [k][j] = cls_W1[j][k]
  __shared__ float sW2[64];      // [c*32+j]
  __shared__ float sB1[32];

  const int tid = threadIdx.x, lane = tid & 63, w = tid >> 6;
  const int isf32 = flagp[0];

  for (int i = tid; i < 4096; i += 256) {
    int o = i >> 6, k = i & 63;
    sWT[k * 64 + o] = (u32)ld16(rgcnW, o * 64 + k, isf32) | ((u32)ld16(rgcnW, 4096 + o * 64 + k, isf32) << 16);
  }
  for (int i = tid; i < 2048; i += 256) {
    int j = i >> 6, k = i & 63;
    sW1T[k * 32 + j] = ld16(W1, j * 64 + k, isf32);
  }
  if (tid < 64) sW2[tid] = ldf(W2, tid, isf32);
  if (tid < 32) sB1[tid] = ldf(b1, tid, isf32);
  float b20 = ldf(b2, 0, isf32), b21 = ldf(b2, 1, isf32);
  __syncthreads();

  for (int nd = blockIdx.x * 4 + w; nd < n; nd += gridDim.x * 4) {
    int beg = offs[nd], end = offs[nd + 1];
    float acc0 = 0.f, acc1 = 0.f;
    int c0 = 0, c1 = 0;
    for (int j0 = beg; j0 < end; j0 += 64) {
      int idx = j0 + lane;
      int p = (idx < end) ? packed[idx] : 0;
      int cn = min(64, end - j0);
      for (int t = 0; t < cn; ++t) {
        int pj = __shfl(p, t);
        int s = pj & 0x1FFFF;
        float vv = x[(size_t)s * 64 + lane];
        if (pj >> 17) { acc1 += vv; c1++; } else { acc0 += vv; c0++; }
      }
    }
    float a0 = acc0 * (1.f / (float)(c0 > 1 ? c0 : 1));
    float a1 = acc1 * (1.f / (float)(c1 > 1 ? c1 : 1));

    // y[h] = sum_k a0[k]*W0[h][k] + a1[k]*W1[h][k]
    float y = 0.f;
    #pragma unroll 8
    for (int k = 0; k < 64; ++k) {
      float v0 = __shfl(a0, k), v1 = __shfl(a1, k);
      u32 pk = sWT[k * 64 + lane];
      y = fmaf(v0, bl(pk), y);
      y = fmaf(v1, bh(pk), y);
    }
    float x2 = leaky(y * 0.5f);

    // h1[j] = leaky(sum_k x2[k]*cls_W1[j][k] + b1[j])
    float hh = 0.f;
    const int jj = lane & 31;
    #pragma unroll 8
    for (int k = 0; k < 64; ++k) {
      float xk = __shfl(x2, k);
      hh = fmaf(xk, b2f(sW1T[k * 32 + jj]), hh);
    }
    hh = leaky(hh + sB1[jj]);

    float t0 = hh * sW2[jj], t1 = hh * sW2[32 + jj];
    if (lane >= 32) { t0 = 0.f; t1 = 0.f; }
    #pragma unroll
    for (int o = 32; o > 0; o >>= 1) { t0 += __shfl_down(t0, o); t1 += __shfl_down(t1, o); }
    if (lane == 0) {
      float o0 = t0 + b20, o1 = t1 + b21;
      if (isf32) {
        float2 q; q.x = o0; q.y = o1;
        ((float2*)outp)[nd] = q;
      } else {
        ((u32*)outp)[nd] = (u32)f2b(o0) | ((u32)f2b(o1) << 16);
      }
    }
  }
}

// ---------------------------------------------------------------------------
extern "C" void kernel_launch(void* const* d_in, const int* in_sizes, int n_in,
                              void* d_out, int out_size, void* d_ws, size_t ws_size,
                              hipStream_t stream)
{
  const void* des  = d_in[0];
  const void* nump = d_in[1];
  const void* catp = d_in[2];
  const int* ei   = (const int*)d_in[3];
  const int* et   = (const int*)d_in[4];
  const void* desW = d_in[5];
  const void* desB = d_in[6];
  const void* numW = d_in[7];
  const void* numB = d_in[8];
  const void* catW = d_in[9];
  const void* catB = d_in[10];
  const void* dg  = d_in[11];
  const void* dbe = d_in[12];
  const void* dm  = d_in[13];
  const void* dv  = d_in[14];
  const void* ng  = d_in[15];
  const void* nbe = d_in[16];
  const void* nm  = d_in[17];
  const void* nv  = d_in[18];
  const void* cg  = d_in[19];
  const void* cbe = d_in[20];
  const void* cm  = d_in[21];
  const void* cv  = d_in[22];
  const void* rgcnW = d_in[23];
  const void* W1 = d_in[24];
  const void* b1 = d_in[25];
  const void* W2 = d_in[26];
  const void* b2 = d_in[27];

  const int N = in_sizes[1] / 5;   // num is (N,5)
  const int E = in_sizes[4];       // edge_type is (E,)

  // workspace layout
  char* ws = (char*)d_ws;
  int* flag  = (int*)ws;                   size_t off = 256;
  float* x   = (float*)(ws + off);         off += (size_t)N * 64 * 4;
  int* deg   = (int*)(ws + off);           off += (size_t)N * 4;
  int* cur   = (int*)(ws + off);           off += (size_t)N * 4;
  int* offs  = (int*)(ws + off);           off += (size_t)(N + 1) * 4;
  off = (off + 255) & ~(size_t)255;
  int* packed = (int*)(ws + off);

  hipMemsetAsync(deg, 0, (size_t)N * 8, stream);  // zero deg + cur (adjacent)

  k_detect<<<1, 64, 0, stream>>>((const u32*)des, flag);
  k_fuse<<<256, 256, 0, stream>>>(des, nump, catp, desW, desB, numW, numB, catW, catB,
                                  dg, dbe, dm, dv, ng, nbe, nm, nv, cg, cbe, cm, cv,
                                  flag, x, N);
  k_hist<<<(E + 255) / 256, 256, 0, stream>>>(ei, E, deg);
  k_scan<<<1, 1024, 0, stream>>>(deg, offs, N);
  k_place<<<(E + 255) / 256, 256, 0, stream>>>(ei, et, E, offs, cur, packed);
  k_agg<<<768, 256, 0, stream>>>(x, offs, packed, rgcnW, W1, b1, W2, b2, flag, (void*)d_out, N);
}

// Round 5
// 1188.540 us; speedup vs baseline: 1.6171x; 1.6171x over previous
//
#include <hip/hip_runtime.h>

typedef unsigned int u32;
typedef unsigned short u16;

#define NEG 0.01f
#define BN_EPS 1e-5f

typedef __attribute__((ext_vector_type(8))) short bf16x8;
typedef __attribute__((ext_vector_type(4))) float f32x4;

__device__ __forceinline__ float bl(u32 u){ union { u32 i; float f; } c; c.i = u << 16; return c.f; }
__device__ __forceinline__ float bh(u32 u){ union { u32 i; float f; } c; c.i = u & 0xFFFF0000u; return c.f; }
__device__ __forceinline__ float b2f(u16 u){ union { u32 i; float f; } c; c.i = ((u32)u) << 16; return c.f; }
__device__ __forceinline__ u16 f2b(float f){
  union { float f; u32 i; } c; c.f = f;
  u32 t = c.i + 0x7FFFu + ((c.i >> 16) & 1u);
  return (u16)(t >> 16);
}
__device__ __forceinline__ float leaky(float v){ return v > 0.f ? v : NEG * v; }

// ---------------------------------------------------------------------------
// Kernel 0: convert desW (64x768 fp32) -> bf16 in workspace (L2-resident B).
// ---------------------------------------------------------------------------
__global__ void k_prep(const float* __restrict__ desWf, u16* __restrict__ desW16)
{
  int i = blockIdx.x * 256 + threadIdx.x;   // grid covers 49152
  if (i < 64 * 768) desW16[i] = f2b(desWf[i]);
}

// ---------------------------------------------------------------------------
// Kernel 1: fusion GEMM via MFMA (fp32 inputs).
// x16[node][64] (bf16) = leaky(bn(des@desW^T)) + leaky(bn(num@numW^T)) + leaky(bn(cat@catW^T))
// Block = 64 rows (4 waves x 16 rows). A: fp32 global loads + on-the-fly bf16
// cvt. B: pre-converted bf16 desW16 straight from global (L2). No big LDS ->
// good occupancy. num/cat branches per-row into small padded LDS tile.
// ---------------------------------------------------------------------------
__global__ __launch_bounds__(256) void k_fuse(
    const float* __restrict__ des, const float* __restrict__ nump, const float* __restrict__ catp,
    const u16* __restrict__ desW16, const float* __restrict__ desB,
    const float* __restrict__ numW, const float* __restrict__ numB,
    const float* __restrict__ catW, const float* __restrict__ catB,
    const float* __restrict__ dg, const float* __restrict__ dbe, const float* __restrict__ dm, const float* __restrict__ dv,
    const float* __restrict__ ng, const float* __restrict__ nbe, const float* __restrict__ nm, const float* __restrict__ nv,
    const float* __restrict__ cg, const float* __restrict__ cbe, const float* __restrict__ cm, const float* __restrict__ cv,
    u16* __restrict__ x16, int n)
{
  __shared__ float ync[64][66];   // [block-local row][channel]; stride 66 -> <=2-way banks (free)

  const int tid  = threadIdx.x;
  const int lane = tid & 63;
  const int w    = tid >> 6;
  const int quad = lane >> 4;
  const int l15  = lane & 15;
  const int rowbase = blockIdx.x * 64 + 16 * w;

  // ---- num/cat branches: lane = channel, wave covers its own 16 rows ----
  {
    float nw[5], cw[6];
    #pragma unroll
    for (int j = 0; j < 5; ++j) nw[j] = numW[lane * 5 + j];
    #pragma unroll
    for (int j = 0; j < 6; ++j) cw[j] = catW[lane * 6 + j];
    float An = ng[lane] * rsqrtf(nv[lane] + BN_EPS);
    float Bn = (numB[lane] - nm[lane]) * An + nbe[lane];
    float Ac = cg[lane] * rsqrtf(cv[lane] + BN_EPS);
    float Bc = (catB[lane] - cm[lane]) * Ac + cbe[lane];
    for (int m = 0; m < 16; ++m) {
      int node = rowbase + m; if (node > n - 1) node = n - 1;
      float yn = 0.f, yc = 0.f;
      #pragma unroll
      for (int j = 0; j < 5; ++j) yn = fmaf(nump[node * 5 + j], nw[j], yn);
      #pragma unroll
      for (int j = 0; j < 6; ++j) yc = fmaf(catp[node * 6 + j], cw[j], yc);
      ync[16 * w + m][lane] = leaky(yn * An + Bn) + leaky(yc * Ac + Bc);
    }
  }

  // ---- per-lane per-tile BN affine for des branch (channel nn = 16t + l15) ----
  float Ad4[4], Bd4[4];
  #pragma unroll
  for (int t = 0; t < 4; ++t) {
    int nn = 16 * t + l15;
    float A = dg[nn] * rsqrtf(dv[nn] + BN_EPS);
    Ad4[t] = A;
    Bd4[t] = (desB[nn] - dm[nn]) * A + dbe[nn];
  }
  __syncthreads();

  // ---- MFMA K-loop ----
  int rowA = rowbase + l15; if (rowA > n - 1) rowA = n - 1;
  const float* aP  = des + (size_t)rowA * 768 + quad * 8;
  const u16* b0P = desW16 + (size_t)(l15)      * 768 + quad * 8;
  const u16* b1P = desW16 + (size_t)(16 + l15) * 768 + quad * 8;
  const u16* b2P = desW16 + (size_t)(32 + l15) * 768 + quad * 8;
  const u16* b3P = desW16 + (size_t)(48 + l15) * 768 + quad * 8;

  f32x4 acc[4];
  #pragma unroll
  for (int t = 0; t < 4; ++t) acc[t] = (f32x4){0.f, 0.f, 0.f, 0.f};

  #pragma unroll 2
  for (int k = 0; k < 768; k += 32) {
    float4 x0 = *(const float4*)(aP + k);
    float4 x1 = *(const float4*)(aP + k + 4);
    bf16x8 a;
    a[0] = (short)f2b(x0.x); a[1] = (short)f2b(x0.y);
    a[2] = (short)f2b(x0.z); a[3] = (short)f2b(x0.w);
    a[4] = (short)f2b(x1.x); a[5] = (short)f2b(x1.y);
    a[6] = (short)f2b(x1.z); a[7] = (short)f2b(x1.w);
    acc[0] = __builtin_amdgcn_mfma_f32_16x16x32_bf16(a, *(const bf16x8*)(b0P + k), acc[0], 0, 0, 0);
    acc[1] = __builtin_amdgcn_mfma_f32_16x16x32_bf16(a, *(const bf16x8*)(b1P + k), acc[1], 0, 0, 0);
    acc[2] = __builtin_amdgcn_mfma_f32_16x16x32_bf16(a, *(const bf16x8*)(b2P + k), acc[2], 0, 0, 0);
    acc[3] = __builtin_amdgcn_mfma_f32_16x16x32_bf16(a, *(const bf16x8*)(b3P + k), acc[3], 0, 0, 0);
  }

  // ---- epilogue: D[m][nn], m = quad*4 + r, nn = 16t + l15 ----
  #pragma unroll
  for (int t = 0; t < 4; ++t) {
    #pragma unroll
    for (int r = 0; r < 4; ++r) {
      int m = quad * 4 + r;
      int node = rowbase + m;
      if (node < n) {
        int nn = 16 * t + l15;
        float v = leaky(acc[t][r] * Ad4[t] + Bd4[t]) + ync[16 * w + m][nn];
        x16[(size_t)node * 64 + nn] = f2b(v);
      }
    }
  }
}

// ---------------------------------------------------------------------------
// Kernel 2: per-(dst,rel) histogram. bin = dst*2 + rel
// ---------------------------------------------------------------------------
__global__ void k_hist(const int* __restrict__ ei, const int* __restrict__ et,
                       int E, int* __restrict__ deg2)
{
  int e = blockIdx.x * 256 + threadIdx.x;
  if (e < E) atomicAdd(&deg2[ei[E + e] * 2 + et[e]], 1);
}

// ---------------------------------------------------------------------------
// Kernel 3: exclusive prefix sum over M=2N bins (single block, x4 vectorized)
// ---------------------------------------------------------------------------
__global__ __launch_bounds__(1024) void k_scan(const int* __restrict__ deg2, int* __restrict__ offs2, int M)
{
  __shared__ int wsum[16];
  __shared__ int carry;
  const int tid = threadIdx.x, lane = tid & 63, w = tid >> 6;
  if (tid == 0) carry = 0;
  __syncthreads();
  for (int base = 0; base < M; base += 4096) {
    int idx = base + tid * 4;
    int4 v = {0, 0, 0, 0};
    if (idx < M) v = *(const int4*)(deg2 + idx);   // M % 4 == 0
    int s4 = v.x + v.y + v.z + v.w;
    int s = s4;
    #pragma unroll
    for (int o = 1; o < 64; o <<= 1) { int t = __shfl_up(s, o); if (lane >= o) s += t; }
    if (lane == 63) wsum[w] = s;
    __syncthreads();
    if (w == 0 && lane < 16) {
      int t = wsum[lane];
      #pragma unroll
      for (int o = 1; o < 16; o <<= 1) { int u = __shfl_up(t, o); if (lane >= o) t += u; }
      wsum[lane] = t;
    }
    __syncthreads();
    int wbase = (w == 0) ? 0 : wsum[w - 1];
    int ebase = carry + wbase + (s - s4);
    if (idx < M) {
      int4 o4;
      o4.x = ebase;
      o4.y = ebase + v.x;
      o4.z = ebase + v.x + v.y;
      o4.w = ebase + v.x + v.y + v.z;
      *(int4*)(offs2 + idx) = o4;
    }
    __syncthreads();
    if (tid == 0) carry += wsum[15];
    __syncthreads();
  }
  if (tid == 0) offs2[M] = carry;
}

// ---------------------------------------------------------------------------
// Kernel 4: CSR placement sorted by (dst, rel). packed[pos] = src
// ---------------------------------------------------------------------------
__global__ void k_place(const int* __restrict__ ei, const int* __restrict__ et, int E,
                        const int* __restrict__ offs2, int* __restrict__ cur2, int* __restrict__ packed)
{
  int e = blockIdx.x * 256 + threadIdx.x;
  if (e < E) {
    int bin = ei[E + e] * 2 + et[e];
    int pos = offs2[bin] + atomicAdd(&cur2[bin], 1);
    packed[pos] = ei[e];
  }
}

// ---------------------------------------------------------------------------
// Kernel 5: per-node aggregation (wave-per-node, lane = channel), bf16 gather,
// 4-way unrolled; relation transform + mean + classifier fused. fp32 weights
// staged to bf16 LDS (precision validated in R2); fp32 float2 output.
// ---------------------------------------------------------------------------
__global__ __launch_bounds__(256) void k_agg(
    const u16* __restrict__ x16, const int* __restrict__ offs2, const int* __restrict__ packed,
    const float* __restrict__ rgcnW, const float* __restrict__ W1, const float* __restrict__ b1,
    const float* __restrict__ W2, const float* __restrict__ b2,
    float2* __restrict__ out, int n)
{
  __shared__ u32 sWT[64 * 64];   // [k][h] : low16 = W0[h][k], high16 = W1[h][k] (bf16)
  __shared__ u16 sW1T[64 * 32];  // [k][j] = cls_W1[j][k] (bf16)
  __shared__ float sW2[64];
  __shared__ float sB1[32];

  const int tid = threadIdx.x, lane = tid & 63, w = tid >> 6;

  for (int i = tid; i < 4096; i += 256) {
    int o = i >> 6, k = i & 63;
    sWT[k * 64 + o] = (u32)f2b(rgcnW[o * 64 + k]) | ((u32)f2b(rgcnW[4096 + o * 64 + k]) << 16);
  }
  for (int i = tid; i < 2048; i += 256) {
    int j = i >> 6, k = i & 63;
    sW1T[k * 32 + j] = f2b(W1[j * 64 + k]);
  }
  if (tid < 64) sW2[tid] = W2[tid];
  if (tid < 32) sB1[tid] = b1[tid];
  float b20 = b2[0], b21 = b2[1];
  __syncthreads();

  for (int nd = blockIdx.x * 4 + w; nd < n; nd += gridDim.x * 4) {
    int o0 = offs2[nd * 2], o1 = offs2[nd * 2 + 1], o2 = offs2[nd * 2 + 2];
    float accs[2] = {0.f, 0.f};

    #pragma unroll
    for (int rel = 0; rel < 2; ++rel) {
      int beg = rel ? o1 : o0;
      int end = rel ? o2 : o1;
      float acc = 0.f;
      for (int j0 = beg; j0 < end; j0 += 64) {
        int idx = j0 + lane;
        int p = (idx < end) ? packed[idx] : 0;
        p = (p < 0) ? 0 : ((p > n - 1) ? (n - 1) : p);   // clamp: no wild reads
        int cn = end - j0; if (cn > 64) cn = 64;
        int t = 0;
        for (; t + 4 <= cn; t += 4) {
          int s0 = __shfl(p, t), s1 = __shfl(p, t + 1), s2 = __shfl(p, t + 2), s3 = __shfl(p, t + 3);
          float v0 = b2f(x16[(size_t)s0 * 64 + lane]);
          float v1 = b2f(x16[(size_t)s1 * 64 + lane]);
          float v2 = b2f(x16[(size_t)s2 * 64 + lane]);
          float v3 = b2f(x16[(size_t)s3 * 64 + lane]);
          acc += (v0 + v1) + (v2 + v3);
        }
        for (; t < cn; ++t) {
          int s0 = __shfl(p, t);
          acc += b2f(x16[(size_t)s0 * 64 + lane]);
        }
      }
      accs[rel] = acc;
    }

    int c0 = o1 - o0, c1 = o2 - o1;
    float a0 = accs[0] * (1.f / (float)(c0 > 1 ? c0 : 1));
    float a1 = accs[1] * (1.f / (float)(c1 > 1 ? c1 : 1));

    // y[h] = sum_k a0[k]*W0[h][k] + a1[k]*W1[h][k]
    float y = 0.f;
    #pragma unroll 8
    for (int k = 0; k < 64; ++k) {
      float v0 = __shfl(a0, k), v1 = __shfl(a1, k);
      u32 pk = sWT[k * 64 + lane];
      y = fmaf(v0, bl(pk), y);
      y = fmaf(v1, bh(pk), y);
    }
    float x2 = leaky(y * 0.5f);

    // h1[j] = leaky(sum_k x2[k]*cls_W1[j][k] + b1[j])
    float hh = 0.f;
    const int jj = lane & 31;
    #pragma unroll 8
    for (int k = 0; k < 64; ++k) {
      float xk = __shfl(x2, k);
      hh = fmaf(xk, b2f(sW1T[k * 32 + jj]), hh);
    }
    hh = leaky(hh + sB1[jj]);

    float t0 = hh * sW2[jj], t1 = hh * sW2[32 + jj];
    if (lane >= 32) { t0 = 0.f; t1 = 0.f; }
    #pragma unroll
    for (int o = 32; o > 0; o >>= 1) { t0 += __shfl_down(t0, o); t1 += __shfl_down(t1, o); }
    if (lane == 0) {
      float2 q; q.x = t0 + b20; q.y = t1 + b21;
      out[nd] = q;
    }
  }
}

// ---------------------------------------------------------------------------
extern "C" void kernel_launch(void* const* d_in, const int* in_sizes, int n_in,
                              void* d_out, int out_size, void* d_ws, size_t ws_size,
                              hipStream_t stream)
{
  const float* des  = (const float*)d_in[0];
  const float* nump = (const float*)d_in[1];
  const float* catp = (const float*)d_in[2];
  const int* ei   = (const int*)d_in[3];
  const int* et   = (const int*)d_in[4];
  const float* desW = (const float*)d_in[5];
  const float* desB = (const float*)d_in[6];
  const float* numW = (const float*)d_in[7];
  const float* numB = (const float*)d_in[8];
  const float* catW = (const float*)d_in[9];
  const float* catB = (const float*)d_in[10];
  const float* dg  = (const float*)d_in[11];
  const float* dbe = (const float*)d_in[12];
  const float* dm  = (const float*)d_in[13];
  const float* dv  = (const float*)d_in[14];
  const float* ng  = (const float*)d_in[15];
  const float* nbe = (const float*)d_in[16];
  const float* nm  = (const float*)d_in[17];
  const float* nv  = (const float*)d_in[18];
  const float* cg  = (const float*)d_in[19];
  const float* cbe = (const float*)d_in[20];
  const float* cm  = (const float*)d_in[21];
  const float* cv  = (const float*)d_in[22];
  const float* rgcnW = (const float*)d_in[23];
  const float* W1 = (const float*)d_in[24];
  const float* b1 = (const float*)d_in[25];
  const float* W2 = (const float*)d_in[26];
  const float* b2 = (const float*)d_in[27];

  const int N = in_sizes[1] / 5;   // num is (N,5)
  const int E = in_sizes[4];       // edge_type is (E,)
  const int M = 2 * N;             // (dst, rel) bins

  // workspace layout
  char* ws = (char*)d_ws;
  u16* desW16 = (u16*)ws;                  size_t off = (size_t)64 * 768 * 2;   // 98304 (256-mult)
  u16* x16   = (u16*)(ws + off);           off += (size_t)N * 64 * 2;
  int* deg2  = (int*)(ws + off);           off += (size_t)M * 4;
  int* cur2  = (int*)(ws + off);           off += (size_t)M * 4;
  int* offs2 = (int*)(ws + off);           off += (size_t)(M + 1) * 4;
  off = (off + 255) & ~(size_t)255;
  int* packed = (int*)(ws + off);

  hipMemsetAsync(deg2, 0, (size_t)M * 8, stream);     // zero deg2 + cur2 (adjacent)
  hipMemsetAsync(packed, 0, (size_t)E * 4, stream);   // no garbage slots

  k_prep<<<(64 * 768 + 255) / 256, 256, 0, stream>>>(desW, desW16);
  k_fuse<<<(N + 63) / 64, 256, 0, stream>>>(des, nump, catp, desW16, desB, numW, numB, catW, catB,
                                            dg, dbe, dm, dv, ng, nbe, nm, nv, cg, cbe, cm, cv,
                                            x16, N);
  k_hist<<<(E + 255) / 256, 256, 0, stream>>>(ei, et, E, deg2);
  k_scan<<<1, 1024, 0, stream>>>(deg2, offs2, M);
  k_place<<<(E + 255) / 256, 256, 0, stream>>>(ei, et, E, offs2, cur2, packed);
  k_agg<<<2048, 256, 0, stream>>>(x16, offs2, packed, rgcnW, W1, b1, W2, b2, (float2*)d_out, N);
}

// Round 6
// 947.123 us; speedup vs baseline: 2.0293x; 1.2549x over previous
//
#include <hip/hip_runtime.h>

typedef unsigned int u32;
typedef unsigned short u16;

#define NEG 0.01f
#define BN_EPS 1e-5f

typedef __attribute__((ext_vector_type(8))) short bf16x8;
typedef __attribute__((ext_vector_type(4))) float f32x4;

__device__ __forceinline__ float bl(u32 u){ union { u32 i; float f; } c; c.i = u << 16; return c.f; }
__device__ __forceinline__ float bh(u32 u){ union { u32 i; float f; } c; c.i = u & 0xFFFF0000u; return c.f; }
__device__ __forceinline__ float b2f(u16 u){ union { u32 i; float f; } c; c.i = ((u32)u) << 16; return c.f; }
__device__ __forceinline__ u16 f2b(float f){
  union { float f; u32 i; } c; c.f = f;
  u32 t = c.i + 0x7FFFu + ((c.i >> 16) & 1u);
  return (u16)(t >> 16);
}
__device__ __forceinline__ float leaky(float v){ return v > 0.f ? v : NEG * v; }

// ---------------------------------------------------------------------------
// Kernel 0: weight prep (fp32 -> bf16 tables in ws).
//  [0,49152)          : desW16[64][768]
//  [49152,57344)      : Wmlp[64][128]  row h: {rgcnW0[h][0..63], rgcnW1[h][0..63]}
//  [57344,59392)      : W1p[32][64]    cls_W1 rows
// ---------------------------------------------------------------------------
__global__ void k_prep(const float* __restrict__ desWf, const float* __restrict__ rgcnW,
                       const float* __restrict__ W1, u16* __restrict__ tab)
{
  int i = blockIdx.x * 256 + threadIdx.x;
  if (i < 49152) {
    tab[i] = f2b(desWf[i]);
  } else if (i < 57344) {
    int j = i - 49152;            // h*128 + k
    int h = j >> 7, k = j & 127;
    tab[i] = f2b(rgcnW[(k >= 64 ? 4096 : 0) + h * 64 + (k & 63)]);
  } else if (i < 59392) {
    tab[i] = f2b(W1[i - 57344]);
  }
}

// ---------------------------------------------------------------------------
// Kernel 1: fusion GEMM via MFMA (fp32 inputs) -> x16[node][64] bf16.
// (unchanged from R5 pass)
// ---------------------------------------------------------------------------
__global__ __launch_bounds__(256) void k_fuse(
    const float* __restrict__ des, const float* __restrict__ nump, const float* __restrict__ catp,
    const u16* __restrict__ desW16, const float* __restrict__ desB,
    const float* __restrict__ numW, const float* __restrict__ numB,
    const float* __restrict__ catW, const float* __restrict__ catB,
    const float* __restrict__ dg, const float* __restrict__ dbe, const float* __restrict__ dm, const float* __restrict__ dv,
    const float* __restrict__ ng, const float* __restrict__ nbe, const float* __restrict__ nm, const float* __restrict__ nv,
    const float* __restrict__ cg, const float* __restrict__ cbe, const float* __restrict__ cm, const float* __restrict__ cv,
    u16* __restrict__ x16, int n)
{
  __shared__ float ync[64][66];

  const int tid  = threadIdx.x;
  const int lane = tid & 63;
  const int w    = tid >> 6;
  const int quad = lane >> 4;
  const int l15  = lane & 15;
  const int rowbase = blockIdx.x * 64 + 16 * w;

  {
    float nw[5], cw[6];
    #pragma unroll
    for (int j = 0; j < 5; ++j) nw[j] = numW[lane * 5 + j];
    #pragma unroll
    for (int j = 0; j < 6; ++j) cw[j] = catW[lane * 6 + j];
    float An = ng[lane] * rsqrtf(nv[lane] + BN_EPS);
    float Bn = (numB[lane] - nm[lane]) * An + nbe[lane];
    float Ac = cg[lane] * rsqrtf(cv[lane] + BN_EPS);
    float Bc = (catB[lane] - cm[lane]) * Ac + cbe[lane];
    for (int m = 0; m < 16; ++m) {
      int node = rowbase + m; if (node > n - 1) node = n - 1;
      float yn = 0.f, yc = 0.f;
      #pragma unroll
      for (int j = 0; j < 5; ++j) yn = fmaf(nump[node * 5 + j], nw[j], yn);
      #pragma unroll
      for (int j = 0; j < 6; ++j) yc = fmaf(catp[node * 6 + j], cw[j], yc);
      ync[16 * w + m][lane] = leaky(yn * An + Bn) + leaky(yc * Ac + Bc);
    }
  }

  float Ad4[4], Bd4[4];
  #pragma unroll
  for (int t = 0; t < 4; ++t) {
    int nn = 16 * t + l15;
    float A = dg[nn] * rsqrtf(dv[nn] + BN_EPS);
    Ad4[t] = A;
    Bd4[t] = (desB[nn] - dm[nn]) * A + dbe[nn];
  }
  __syncthreads();

  int rowA = rowbase + l15; if (rowA > n - 1) rowA = n - 1;
  const float* aP  = des + (size_t)rowA * 768 + quad * 8;
  const u16* b0P = desW16 + (size_t)(l15)      * 768 + quad * 8;
  const u16* b1P = desW16 + (size_t)(16 + l15) * 768 + quad * 8;
  const u16* b2P = desW16 + (size_t)(32 + l15) * 768 + quad * 8;
  const u16* b3P = desW16 + (size_t)(48 + l15) * 768 + quad * 8;

  f32x4 acc[4];
  #pragma unroll
  for (int t = 0; t < 4; ++t) acc[t] = (f32x4){0.f, 0.f, 0.f, 0.f};

  #pragma unroll 2
  for (int k = 0; k < 768; k += 32) {
    float4 x0 = *(const float4*)(aP + k);
    float4 x1 = *(const float4*)(aP + k + 4);
    bf16x8 a;
    a[0] = (short)f2b(x0.x); a[1] = (short)f2b(x0.y);
    a[2] = (short)f2b(x0.z); a[3] = (short)f2b(x0.w);
    a[4] = (short)f2b(x1.x); a[5] = (short)f2b(x1.y);
    a[6] = (short)f2b(x1.z); a[7] = (short)f2b(x1.w);
    acc[0] = __builtin_amdgcn_mfma_f32_16x16x32_bf16(a, *(const bf16x8*)(b0P + k), acc[0], 0, 0, 0);
    acc[1] = __builtin_amdgcn_mfma_f32_16x16x32_bf16(a, *(const bf16x8*)(b1P + k), acc[1], 0, 0, 0);
    acc[2] = __builtin_amdgcn_mfma_f32_16x16x32_bf16(a, *(const bf16x8*)(b2P + k), acc[2], 0, 0, 0);
    acc[3] = __builtin_amdgcn_mfma_f32_16x16x32_bf16(a, *(const bf16x8*)(b3P + k), acc[3], 0, 0, 0);
  }

  #pragma unroll
  for (int t = 0; t < 4; ++t) {
    #pragma unroll
    for (int r = 0; r < 4; ++r) {
      int m = quad * 4 + r;
      int node = rowbase + m;
      if (node < n) {
        int nn = 16 * t + l15;
        float v = leaky(acc[t][r] * Ad4[t] + Bd4[t]) + ync[16 * w + m][nn];
        x16[(size_t)node * 64 + nn] = f2b(v);
      }
    }
  }
}

// ---------------------------------------------------------------------------
// Kernel 2: per-(dst,rel) histogram. bin = dst*2 + rel
// ---------------------------------------------------------------------------
__global__ void k_hist(const int* __restrict__ ei, const int* __restrict__ et,
                       int E, int* __restrict__ deg2)
{
  int e = blockIdx.x * 256 + threadIdx.x;
  if (e < E) atomicAdd(&deg2[ei[E + e] * 2 + et[e]], 1);
}

// ---------------------------------------------------------------------------
// Kernel 3: exclusive prefix sum over M=2N bins (single block, x4 vectorized)
// ---------------------------------------------------------------------------
__global__ __launch_bounds__(1024) void k_scan(const int* __restrict__ deg2, int* __restrict__ offs2, int M)
{
  __shared__ int wsum[16];
  __shared__ int carry;
  const int tid = threadIdx.x, lane = tid & 63, w = tid >> 6;
  if (tid == 0) carry = 0;
  __syncthreads();
  for (int base = 0; base < M; base += 4096) {
    int idx = base + tid * 4;
    int4 v = {0, 0, 0, 0};
    if (idx < M) v = *(const int4*)(deg2 + idx);
    int s4 = v.x + v.y + v.z + v.w;
    int s = s4;
    #pragma unroll
    for (int o = 1; o < 64; o <<= 1) { int t = __shfl_up(s, o); if (lane >= o) s += t; }
    if (lane == 63) wsum[w] = s;
    __syncthreads();
    if (w == 0 && lane < 16) {
      int t = wsum[lane];
      #pragma unroll
      for (int o = 1; o < 16; o <<= 1) { int u = __shfl_up(t, o); if (lane >= o) t += u; }
      wsum[lane] = t;
    }
    __syncthreads();
    int wbase = (w == 0) ? 0 : wsum[w - 1];
    int ebase = carry + wbase + (s - s4);
    if (idx < M) {
      int4 o4;
      o4.x = ebase;
      o4.y = ebase + v.x;
      o4.z = ebase + v.x + v.y;
      o4.w = ebase + v.x + v.y + v.z;
      *(int4*)(offs2 + idx) = o4;
    }
    __syncthreads();
    if (tid == 0) carry += wsum[15];
    __syncthreads();
  }
  if (tid == 0) offs2[M] = carry;
}

// ---------------------------------------------------------------------------
// Kernel 4: CSR placement sorted by (dst, rel). packed[pos] = src
// ---------------------------------------------------------------------------
__global__ void k_place(const int* __restrict__ ei, const int* __restrict__ et, int E,
                        const int* __restrict__ offs2, int* __restrict__ cur2, int* __restrict__ packed)
{
  int e = blockIdx.x * 256 + threadIdx.x;
  if (e < E) {
    int bin = ei[E + e] * 2 + et[e];
    int pos = offs2[bin] + atomicAdd(&cur2[bin], 1);
    packed[pos] = ei[e];
  }
}

// ---------------------------------------------------------------------------
// Kernel 5: pure gather/mean. Wave per node; lane = channel-pair (c=lane&31),
// half-wave = edge substream -> one u32 wave-load gathers TWO edges' rows.
// Writes agg[node][64] u32 words (= 128 bf16: [rel0 ch0..63, rel1 ch0..63]).
// No LDS, no shfl-MLP -> max occupancy, minimal non-VMEM work.
// ---------------------------------------------------------------------------
__global__ __launch_bounds__(256) void k_agg(
    const u16* __restrict__ x16, const int* __restrict__ offs2, const int* __restrict__ packed,
    u32* __restrict__ agg, int n)
{
  const int tid = threadIdx.x, lane = tid & 63, w = tid >> 6;
  const int c = lane & 31, half = lane >> 5;

  for (int nd = blockIdx.x * 4 + w; nd < n; nd += gridDim.x * 4) {
    int o0 = offs2[nd * 2], o1 = offs2[nd * 2 + 1], o2 = offs2[nd * 2 + 2];
    float aE[2], aO[2];

    #pragma unroll
    for (int rel = 0; rel < 2; ++rel) {
      int beg = rel ? o1 : o0;
      int end = rel ? o2 : o1;
      float accE = 0.f, accO = 0.f;
      for (int j0 = beg; j0 < end; j0 += 64) {
        int idx = j0 + lane;
        int p = (idx < end) ? packed[idx] : 0;
        p = (p < 0) ? 0 : ((p > n - 1) ? (n - 1) : p);
        int cn = end - j0; if (cn > 64) cn = 64;
        int t = 0;
        for (; t + 8 <= cn; t += 8) {          // 8 edges: 4 dual-edge loads in flight
          int s0 = __shfl(p, t     + half);
          int s1 = __shfl(p, t + 2 + half);
          int s2 = __shfl(p, t + 4 + half);
          int s3 = __shfl(p, t + 6 + half);
          u32 v0 = *(const u32*)(x16 + (size_t)s0 * 64 + 2 * c);
          u32 v1 = *(const u32*)(x16 + (size_t)s1 * 64 + 2 * c);
          u32 v2 = *(const u32*)(x16 + (size_t)s2 * 64 + 2 * c);
          u32 v3 = *(const u32*)(x16 + (size_t)s3 * 64 + 2 * c);
          accE += (bl(v0) + bl(v1)) + (bl(v2) + bl(v3));
          accO += (bh(v0) + bh(v1)) + (bh(v2) + bh(v3));
        }
        for (; t + 2 <= cn; t += 2) {          // 2 edges per load
          int s0 = __shfl(p, t + half);
          u32 v0 = *(const u32*)(x16 + (size_t)s0 * 64 + 2 * c);
          accE += bl(v0); accO += bh(v0);
        }
        if (t < cn) {                           // odd remainder: half 0 only
          int s0 = __shfl(p, t);
          if (half == 0) {
            u32 v0 = *(const u32*)(x16 + (size_t)s0 * 64 + 2 * c);
            accE += bl(v0); accO += bh(v0);
          }
        }
      }
      accE += __shfl_xor(accE, 32);
      accO += __shfl_xor(accO, 32);
      int cnt = end - beg;
      float sc = 1.f / (float)(cnt > 1 ? cnt : 1);
      aE[rel] = accE * sc;
      aO[rel] = accO * sc;
    }

    float sE = half ? aE[1] : aE[0];
    float sO = half ? aO[1] : aO[0];
    agg[(size_t)nd * 64 + lane] = (u32)f2b(sE) | ((u32)f2b(sO) << 16);
  }
}

// ---------------------------------------------------------------------------
// Kernel 6: batched MFMA MLP.  A = agg[node][128] bf16.
// y64 = leaky(0.5 * A @ Wmlp^T); h32 = leaky(y64 @ W1p^T + b1);
// out2 = h32 @ W2^T + b2.   64 nodes/block (4 waves x 16).
// ---------------------------------------------------------------------------
__global__ __launch_bounds__(256) void k_mlp(
    const u32* __restrict__ agg, const u16* __restrict__ Wmlp, const u16* __restrict__ W1p,
    const float* __restrict__ b1, const float* __restrict__ W2, const float* __restrict__ b2,
    float2* __restrict__ out, int n)
{
  __shared__ __align__(16) u16 h1[4][16][72];   // [wave][node m][ch 0..63], 16B-aligned rows
  __shared__ float h2[4][16][34];               // [wave][node m][j 0..31]

  const int tid = threadIdx.x, lane = tid & 63, w = tid >> 6;
  const int quad = lane >> 4, l15 = lane & 15;
  const int rowbase = blockIdx.x * 64 + 16 * w;

  int rowA = rowbase + l15; if (rowA > n - 1) rowA = n - 1;
  const u16* aRow = (const u16*)(agg + (size_t)rowA * 64);   // 128 bf16

  // ---- GEMM1: [16 nodes x 128] @ [128 -> 64] ----
  f32x4 acc[4];
  #pragma unroll
  for (int t = 0; t < 4; ++t) acc[t] = (f32x4){0.f, 0.f, 0.f, 0.f};
  #pragma unroll
  for (int ks = 0; ks < 4; ++ks) {
    bf16x8 a = *(const bf16x8*)(aRow + ks * 32 + quad * 8);
    #pragma unroll
    for (int t = 0; t < 4; ++t) {
      bf16x8 b = *(const bf16x8*)(Wmlp + (size_t)(16 * t + l15) * 128 + ks * 32 + quad * 8);
      acc[t] = __builtin_amdgcn_mfma_f32_16x16x32_bf16(a, b, acc[t], 0, 0, 0);
    }
  }
  #pragma unroll
  for (int t = 0; t < 4; ++t)
    #pragma unroll
    for (int r = 0; r < 4; ++r) {
      int m = quad * 4 + r;
      h1[w][m][16 * t + l15] = f2b(leaky(0.5f * acc[t][r]));
    }
  __syncthreads();

  // ---- GEMM2: [16 x 64] @ [64 -> 32] ----
  f32x4 acc2[2];
  acc2[0] = (f32x4){0.f, 0.f, 0.f, 0.f};
  acc2[1] = (f32x4){0.f, 0.f, 0.f, 0.f};
  #pragma unroll
  for (int ks = 0; ks < 2; ++ks) {
    bf16x8 a = *(const bf16x8*)(&h1[w][l15][ks * 32 + quad * 8]);
    #pragma unroll
    for (int t = 0; t < 2; ++t) {
      bf16x8 b = *(const bf16x8*)(W1p + (size_t)(16 * t + l15) * 64 + ks * 32 + quad * 8);
      acc2[t] = __builtin_amdgcn_mfma_f32_16x16x32_bf16(a, b, acc2[t], 0, 0, 0);
    }
  }
  #pragma unroll
  for (int t = 0; t < 2; ++t)
    #pragma unroll
    for (int r = 0; r < 4; ++r) {
      int m = quad * 4 + r;
      int j = 16 * t + l15;
      h2[w][m][j] = leaky(acc2[t][r] + b1[j]);
    }
  __syncthreads();

  // ---- final 32 -> 2: lane (quad,l15): node l15, j-range quad*8..+8 ----
  float t0 = 0.f, t1 = 0.f;
  #pragma unroll
  for (int jj = 0; jj < 8; ++jj) {
    int j = quad * 8 + jj;
    float hv = h2[w][l15][j];
    t0 = fmaf(hv, W2[j], t0);
    t1 = fmaf(hv, W2[32 + j], t1);
  }
  t0 += __shfl_xor(t0, 16); t0 += __shfl_xor(t0, 32);
  t1 += __shfl_xor(t1, 16); t1 += __shfl_xor(t1, 32);
  int node = rowbase + l15;
  if (quad == 0 && node < n) {
    float2 q; q.x = t0 + b2[0]; q.y = t1 + b2[1];
    out[node] = q;
  }
}

// ---------------------------------------------------------------------------
extern "C" void kernel_launch(void* const* d_in, const int* in_sizes, int n_in,
                              void* d_out, int out_size, void* d_ws, size_t ws_size,
                              hipStream_t stream)
{
  const float* des  = (const float*)d_in[0];
  const float* nump = (const float*)d_in[1];
  const float* catp = (const float*)d_in[2];
  const int* ei   = (const int*)d_in[3];
  const int* et   = (const int*)d_in[4];
  const float* desW = (const float*)d_in[5];
  const float* desB = (const float*)d_in[6];
  const float* numW = (const float*)d_in[7];
  const float* numB = (const float*)d_in[8];
  const float* catW = (const float*)d_in[9];
  const float* catB = (const float*)d_in[10];
  const float* dg  = (const float*)d_in[11];
  const float* dbe = (const float*)d_in[12];
  const float* dm  = (const float*)d_in[13];
  const float* dv  = (const float*)d_in[14];
  const float* ng  = (const float*)d_in[15];
  const float* nbe = (const float*)d_in[16];
  const float* nm  = (const float*)d_in[17];
  const float* nv  = (const float*)d_in[18];
  const float* cg  = (const float*)d_in[19];
  const float* cbe = (const float*)d_in[20];
  const float* cm  = (const float*)d_in[21];
  const float* cv  = (const float*)d_in[22];
  const float* rgcnW = (const float*)d_in[23];
  const float* W1 = (const float*)d_in[24];
  const float* b1 = (const float*)d_in[25];
  const float* W2 = (const float*)d_in[26];
  const float* b2 = (const float*)d_in[27];

  const int N = in_sizes[1] / 5;   // num is (N,5)
  const int E = in_sizes[4];       // edge_type is (E,)
  const int M = 2 * N;             // (dst, rel) bins

  // workspace layout
  char* ws = (char*)d_ws;
  u16* tab    = (u16*)ws;                  size_t off = (size_t)59392 * 2;      // weight tables
  off = (off + 255) & ~(size_t)255;
  u16* x16    = (u16*)(ws + off);          off += (size_t)N * 64 * 2;
  u32* agg    = (u32*)(ws + off);          off += (size_t)N * 64 * 4;
  int* deg2   = (int*)(ws + off);          off += (size_t)M * 4;
  int* cur2   = (int*)(ws + off);          off += (size_t)M * 4;
  int* offs2  = (int*)(ws + off);          off += (size_t)(M + 1) * 4;
  off = (off + 255) & ~(size_t)255;
  int* packed = (int*)(ws + off);

  u16* desW16 = tab;
  u16* Wmlp   = tab + 49152;
  u16* W1p    = tab + 57344;

  hipMemsetAsync(deg2, 0, (size_t)M * 8, stream);     // zero deg2 + cur2 (adjacent)
  hipMemsetAsync(packed, 0, (size_t)E * 4, stream);   // no garbage slots

  k_prep<<<(59392 + 255) / 256, 256, 0, stream>>>(desW, rgcnW, W1, tab);
  k_fuse<<<(N + 63) / 64, 256, 0, stream>>>(des, nump, catp, desW16, desB, numW, numB, catW, catB,
                                            dg, dbe, dm, dv, ng, nbe, nm, nv, cg, cbe, cm, cv,
                                            x16, N);
  k_hist<<<(E + 255) / 256, 256, 0, stream>>>(ei, et, E, deg2);
  k_scan<<<1, 1024, 0, stream>>>(deg2, offs2, M);
  k_place<<<(E + 255) / 256, 256, 0, stream>>>(ei, et, E, offs2, cur2, packed);
  k_agg<<<2048, 256, 0, stream>>>(x16, offs2, packed, agg, N);
  k_mlp<<<(N + 63) / 64, 256, 0, stream>>>(agg, Wmlp, W1p, b1, W2, b2, (float2*)d_out, N);
}